// Round 1
// baseline (2498.886 us; speedup 1.0000x reference)
//
#include <hip/hip_runtime.h>
#include <cstdint>

#define N_NODESC 50000
#define N_EDGESC 500000
#define E_TOT    550000
#define DIM      144
#define NGRAPH   64
#define EPSV     1e-5f

__device__ __forceinline__ float lrelu(float x){ return x > 0.f ? x : 0.2f*x; }

// ---------------- CSR build (by dst, self-loops appended) ----------------
__global__ void k_count(const int* __restrict__ ei, int* __restrict__ deg){
  int e = blockIdx.x*blockDim.x + threadIdx.x;
  if (e >= E_TOT) return;
  int d = (e < N_EDGESC) ? ei[N_EDGESC + e] : (e - N_EDGESC);
  atomicAdd(&deg[d], 1);
}

__global__ void k_scan(int* __restrict__ degcur, int* __restrict__ row_ptr){
  __shared__ int part[256];
  __shared__ int base[256];
  int t = threadIdx.x;
  const int CH = (N_NODESC + 255)/256;
  int i0 = t*CH, i1 = min(N_NODESC, i0+CH);
  int s = 0;
  for (int i=i0;i<i1;++i) s += degcur[i];
  part[t] = s;
  __syncthreads();
  if (t == 0){ int run = 0; for (int j=0;j<256;++j){ base[j]=run; run+=part[j]; } }
  __syncthreads();
  int run = base[t];
  for (int i=i0;i<i1;++i){ int d = degcur[i]; row_ptr[i]=run; degcur[i]=run; run+=d; }
  if (t == 255) row_ptr[N_NODESC] = E_TOT;
}

__global__ void k_scatter(const int* __restrict__ ei, int* __restrict__ cursor,
                          int* __restrict__ col){
  int e = blockIdx.x*blockDim.x + threadIdx.x;
  if (e >= E_TOT) return;
  int s, d;
  if (e < N_EDGESC){ s = ei[e]; d = ei[N_EDGESC + e]; } else { s = e - N_EDGESC; d = s; }
  int pos = atomicAdd(&cursor[d], 1);
  col[pos] = s;
}

// ---------------- GEMM: out[M,144] = A[M,K] @ W[K,144] (+bias) ----------------
// block: 16 rows x 144 cols, 256 threads, A-tile staged in LDS, W via L1/L2.
__global__ __launch_bounds__(256) void k_gemm(const float* __restrict__ A,
    const float* __restrict__ W, const float* __restrict__ bias,
    float* __restrict__ out, int K){
  extern __shared__ float sA[];           // 16*K floats
  int t = threadIdx.x;
  int m0 = blockIdx.x * 16;
  for (int i=t; i<16*K; i+=256){
    int r = i / K, kk = i - r*K;
    sA[i] = A[(size_t)(m0+r)*K + kk];
  }
  __syncthreads();
  int cg = t & 15, r = t >> 4;
  int c0 = cg * 9;
  float acc[9];
  #pragma unroll
  for (int j=0;j<9;++j) acc[j] = bias ? bias[c0+j] : 0.f;
  const float* sa = sA + r*K;
  for (int k=0;k<K;++k){
    float a = sa[k];
    const float* wr = W + (size_t)k*DIM + c0;
    #pragma unroll
    for (int j=0;j<9;++j) acc[j] = fmaf(a, wr[j], acc[j]);
  }
  float* o = out + (size_t)(m0+r)*DIM + c0;
  #pragma unroll
  for (int j=0;j<9;++j) o[j] = acc[j];
}

// ---------------- attention logits: al_s[n,h] = <hp[n,h,:], a_s[h,:]> ----------------
__global__ void k_attn(const float* __restrict__ hp, const float* __restrict__ a_s,
                       const float* __restrict__ a_d, float* __restrict__ al_s,
                       float* __restrict__ al_d, int H, int C){
  int i = blockIdx.x*blockDim.x + threadIdx.x;
  if (i >= N_NODESC*H) return;
  int n = i / H, h = i - n*H;
  const float* row = hp + (size_t)n*DIM + h*C;
  const float* as = a_s + h*C;
  const float* ad = a_d + h*C;
  float ss = 0.f, sd = 0.f;
  for (int c=0;c<C;++c){ float v = row[c]; ss = fmaf(v, as[c], ss); sd = fmaf(v, ad[c], sd); }
  al_s[i] = ss; al_d[i] = sd;
}

// ---------------- per-node softmax-attention aggregation (+bias+relu) ----------------
__global__ __launch_bounds__(192) void k_aggregate(
    const float* __restrict__ hp, const float* __restrict__ al_s,
    const float* __restrict__ al_d, const int* __restrict__ row_ptr,
    const int* __restrict__ col, const float* __restrict__ bias,
    float* __restrict__ out, int H, int C){
  int n = blockIdx.x;
  int t = threadIdx.x;
  __shared__ float s_max[8];
  __shared__ float red[64*8];
  int p0 = row_ptr[n], p1 = row_ptr[n+1];
  // phase 1: per-head max over incoming edges (64 threads)
  if (t < 64){
    float mx[8];
    for (int h=0;h<H;++h) mx[h] = -3.4e38f;
    for (int e = p0 + t; e < p1; e += 64){
      int s = col[e];
      for (int h=0;h<H;++h){
        float sc = lrelu(al_s[s*H+h] + al_d[n*H+h]);
        mx[h] = fmaxf(mx[h], sc);
      }
    }
    for (int h=0;h<H;++h) red[h*64+t] = mx[h];
  }
  __syncthreads();
  if (t < H){
    float m = red[t*64];
    for (int j=1;j<64;++j) m = fmaxf(m, red[t*64+j]);
    s_max[t] = m;
  }
  __syncthreads();
  // phase 2: one thread per output channel; den computed redundantly per channel
  if (t < DIM){
    int h = t / C;
    float ald = al_d[n*H+h];
    float m = s_max[h];
    float acc = 0.f, den = 0.f;
    for (int e=p0; e<p1; ++e){
      int s = col[e];
      float sc = lrelu(al_s[s*H+h] + ald);
      float ex = __expf(sc - m);
      den += ex;
      acc = fmaf(ex, hp[(size_t)s*DIM + t], acc);
    }
    float v = acc/(den + 1e-16f) + bias[t];
    out[(size_t)n*DIM + t] = fmaxf(v, 0.f);   // fused ReLU
  }
}

// ---------------- batchnorm over nodes ----------------
__global__ __launch_bounds__(256) void k_bnstats(const float* __restrict__ h,
                                                 float* __restrict__ sums){
  __shared__ float ls[2*DIM];
  int t = threadIdx.x;
  for (int i=t;i<2*DIM;i+=256) ls[i] = 0.f;
  __syncthreads();
  const long total = (long)N_NODESC*DIM;
  long per = (total + gridDim.x - 1)/gridDim.x;
  long i0 = (long)blockIdx.x*per, i1 = min(total, i0+per);
  for (long i = i0 + t; i < i1; i += 256){
    float v = h[i]; int c = (int)(i % DIM);
    atomicAdd(&ls[c], v);
    atomicAdd(&ls[DIM+c], v*v);
  }
  __syncthreads();
  for (int i=t;i<2*DIM;i+=256) atomicAdd(&sums[i], ls[i]);
}

__global__ void k_bnapply(float* __restrict__ h, const float* __restrict__ sums,
                          const float* __restrict__ gam, const float* __restrict__ bet){
  long i = (long)blockIdx.x*blockDim.x + threadIdx.x;
  const long total = (long)N_NODESC*DIM;
  if (i >= total) return;
  int c = (int)(i % DIM);
  float mu  = sums[c] * (1.f/N_NODESC);
  float var = sums[DIM+c] * (1.f/N_NODESC) - mu*mu;
  float inv = rsqrtf(var + EPSV);
  h[i] = fmaf((h[i]-mu)*inv, gam[c], bet[c]);
}

// ---------------- per-graph mean pool (batch is sorted) ----------------
__device__ int lbound(const int* a, int n, int v){
  int lo = 0, hi = n;
  while (lo < hi){ int m = (lo+hi) >> 1; if (a[m] < v) lo = m+1; else hi = m; }
  return lo;
}

__global__ __launch_bounds__(192) void k_pool(const float* __restrict__ h,
    const int* __restrict__ batch, float* __restrict__ sums, int* __restrict__ cnts){
  int g = blockIdx.x & 63, part = blockIdx.x >> 6;     // 8 parts per graph
  __shared__ int sb[2];
  if (threadIdx.x == 0){ sb[0] = lbound(batch, N_NODESC, g); sb[1] = lbound(batch, N_NODESC, g+1); }
  __syncthreads();
  int lo = sb[0], hi = sb[1];
  int t = threadIdx.x;
  if (t < DIM){
    float acc = 0.f;
    for (int n = lo + part; n < hi; n += 8) acc += h[(size_t)n*DIM + t];
    atomicAdd(&sums[g*DIM + t], acc);
  }
  if (t == 0 && part == 0) cnts[g] = hi - lo;
}

// ---------------- MLP head: 64x144 -> 72 -> 36 -> 112, BN+ReLU between ----------------
__global__ __launch_bounds__(256) void k_mlp(const float* __restrict__ sums,
    const int* __restrict__ cnts,
    const float* __restrict__ M1, const float* __restrict__ bm1,
    const float* __restrict__ gm1, const float* __restrict__ bb1,
    const float* __restrict__ M2, const float* __restrict__ bm2,
    const float* __restrict__ gm2, const float* __restrict__ bb2,
    const float* __restrict__ M3, const float* __restrict__ bm3,
    float* __restrict__ out){
  __shared__ float sg[64*144];
  __shared__ float s1[64*72];
  __shared__ float s2[64*36];
  __shared__ float stat[144];
  int t = threadIdx.x;
  for (int i=t; i<64*144; i+=256){ int g=i/144; float c=(float)max(cnts[g],1); sg[i]=sums[i]/c; }
  __syncthreads();
  for (int i=t; i<64*72; i+=256){
    int r=i/72, c=i-r*72; float a=bm1[c];
    for (int k=0;k<144;++k) a = fmaf(sg[r*144+k], M1[k*72+c], a);
    s1[i]=a;
  }
  __syncthreads();
  if (t < 72){
    float s=0.f,q=0.f;
    for (int r=0;r<64;++r){ float v=s1[r*72+t]; s+=v; q+=v*v; }
    float mu=s*(1.f/64.f); float var=q*(1.f/64.f)-mu*mu;
    stat[t]=mu; stat[72+t]=rsqrtf(var+EPSV);
  }
  __syncthreads();
  for (int i=t; i<64*72; i+=256){
    int c=i%72; float v=fmaf((s1[i]-stat[c])*stat[72+c], gm1[c], bb1[c]); s1[i]=fmaxf(v,0.f);
  }
  __syncthreads();
  for (int i=t; i<64*36; i+=256){
    int r=i/36, c=i-r*36; float a=bm2[c];
    for (int k=0;k<72;++k) a = fmaf(s1[r*72+k], M2[k*36+c], a);
    s2[i]=a;
  }
  __syncthreads();
  if (t < 36){
    float s=0.f,q=0.f;
    for (int r=0;r<64;++r){ float v=s2[r*36+t]; s+=v; q+=v*v; }
    float mu=s*(1.f/64.f); float var=q*(1.f/64.f)-mu*mu;
    stat[t]=mu; stat[36+t]=rsqrtf(var+EPSV);
  }
  __syncthreads();
  for (int i=t; i<64*36; i+=256){
    int c=i%36; float v=fmaf((s2[i]-stat[c])*stat[36+c], gm2[c], bb2[c]); s2[i]=fmaxf(v,0.f);
  }
  __syncthreads();
  for (int i=t; i<64*112; i+=256){
    int r=i/112, c=i-r*112; float a=bm3[c];
    for (int k=0;k<36;++k) a = fmaf(s2[r*36+k], M3[k*112+c], a);
    out[i]=a;
  }
}

extern "C" void kernel_launch(void* const* d_in, const int* in_sizes, int n_in,
                              void* d_out, int out_size, void* d_ws, size_t ws_size,
                              hipStream_t stream){
  const float* x    = (const float*)d_in[0];
  const int*   ei   = (const int*)d_in[1];
  const int*   batch= (const int*)d_in[2];
  const float* We   = (const float*)d_in[3];
  const float* be   = (const float*)d_in[4];
  const float* Wg   = (const float*)d_in[5];
  const float* a_sg = (const float*)d_in[6];
  const float* a_dg = (const float*)d_in[7];
  const float* bg   = (const float*)d_in[8];
  const float* gam  = (const float*)d_in[9];
  const float* bet  = (const float*)d_in[10];
  const float* W3   = (const float*)d_in[11];
  const float* a_s3 = (const float*)d_in[12];
  const float* a_d3 = (const float*)d_in[13];
  const float* b3   = (const float*)d_in[14];
  const float* gam3 = (const float*)d_in[15];
  const float* bet3 = (const float*)d_in[16];
  const float* M1   = (const float*)d_in[17];
  const float* bm1  = (const float*)d_in[18];
  const float* gm1  = (const float*)d_in[19];
  const float* bb1  = (const float*)d_in[20];
  const float* M2   = (const float*)d_in[21];
  const float* bm2  = (const float*)d_in[22];
  const float* gm2  = (const float*)d_in[23];
  const float* bb2  = (const float*)d_in[24];
  const float* M3   = (const float*)d_in[25];
  const float* bm3  = (const float*)d_in[26];
  float* out = (float*)d_out;

  char* ws = (char*)d_ws;
  size_t off = 0;
  auto alloc = [&](size_t bytes)->char*{
    char* p = ws + off; off += (bytes + 255) & ~(size_t)255; return p;
  };
  float* hA     = (float*)alloc((size_t)N_NODESC*DIM*4);
  float* hp     = (float*)alloc((size_t)N_NODESC*DIM*4);
  float* al_s   = (float*)alloc((size_t)N_NODESC*8*4);
  float* al_d   = (float*)alloc((size_t)N_NODESC*8*4);
  int* row_ptr  = (int*)alloc((size_t)(N_NODESC+1)*4);
  int* cursor   = (int*)alloc((size_t)N_NODESC*4);
  int* col      = (int*)alloc((size_t)E_TOT*4);
  float* bns    = (float*)alloc(2*DIM*4);
  float* psum   = (float*)alloc((size_t)NGRAPH*DIM*4);
  int* pcnt     = (int*)alloc(NGRAPH*4);
  (void)ws_size; (void)n_in; (void)in_sizes; (void)out_size;

  // CSR build (same graph reused by all 4 GAT layers)
  hipMemsetAsync(cursor, 0, (size_t)N_NODESC*4, stream);
  k_count<<<(E_TOT+255)/256, 256, 0, stream>>>(ei, cursor);
  k_scan<<<1, 256, 0, stream>>>(cursor, row_ptr);
  k_scatter<<<(E_TOT+255)/256, 256, 0, stream>>>(ei, cursor, col);

  // embed: hA = x @ We + be
  k_gemm<<<N_NODESC/16, 256, 16*128*4, stream>>>(x, We, be, hA, 128);

  for (int L=0; L<4; ++L){
    const float* W  = (L<3) ? (Wg  + (size_t)L*DIM*DIM) : W3;
    const float* as = (L<3) ? (a_sg + (size_t)L*8*18)   : a_s3;
    const float* ad = (L<3) ? (a_dg + (size_t)L*8*18)   : a_d3;
    const float* bb = (L<3) ? (bg  + L*DIM) : b3;
    const float* gm = (L<3) ? (gam + L*DIM) : gam3;
    const float* bt = (L<3) ? (bet + L*DIM) : bet3;
    int H = (L<3) ? 8 : 1;
    int C = (L<3) ? 18 : 144;
    k_gemm<<<N_NODESC/16, 256, 16*DIM*4, stream>>>(hA, W, nullptr, hp, DIM);
    k_attn<<<(N_NODESC*H+255)/256, 256, 0, stream>>>(hp, as, ad, al_s, al_d, H, C);
    k_aggregate<<<N_NODESC, 192, 0, stream>>>(hp, al_s, al_d, row_ptr, col, bb, hA, H, C);
    hipMemsetAsync(bns, 0, 2*DIM*4, stream);
    k_bnstats<<<256, 256, 0, stream>>>(hA, bns);
    k_bnapply<<<((size_t)N_NODESC*DIM+255)/256, 256, 0, stream>>>(hA, bns, gm, bt);
  }

  hipMemsetAsync(psum, 0, (size_t)NGRAPH*DIM*4, stream);
  k_pool<<<NGRAPH*8, 192, 0, stream>>>(hA, batch, psum, pcnt);
  k_mlp<<<1, 256, 0, stream>>>(psum, pcnt, M1,bm1,gm1,bb1, M2,bm2,gm2,bb2, M3,bm3, out);
}

// Round 2
// 1740.123 us; speedup vs baseline: 1.4360x; 1.4360x over previous
//
#include <hip/hip_runtime.h>
#include <cstdint>

#define N_NODESC 50000
#define N_EDGESC 500000
#define E_TOT    550000
#define DIM      144
#define NGRAPH   64
#define EPSV     1e-5f

__device__ __forceinline__ float lrelu(float x){ return x > 0.f ? x : 0.2f*x; }

// ---------------- CSR build (by dst, self-loops appended) ----------------
__global__ void k_count(const int* __restrict__ ei, int* __restrict__ deg){
  int e = blockIdx.x*blockDim.x + threadIdx.x;
  if (e >= E_TOT) return;
  int d = (e < N_EDGESC) ? ei[N_EDGESC + e] : (e - N_EDGESC);
  atomicAdd(&deg[d], 1);
}

__global__ void k_scan(int* __restrict__ degcur, int* __restrict__ row_ptr){
  __shared__ int part[256];
  __shared__ int base[256];
  int t = threadIdx.x;
  const int CH = (N_NODESC + 255)/256;
  int i0 = t*CH, i1 = min(N_NODESC, i0+CH);
  int s = 0;
  for (int i=i0;i<i1;++i) s += degcur[i];
  part[t] = s;
  __syncthreads();
  if (t == 0){ int run = 0; for (int j=0;j<256;++j){ base[j]=run; run+=part[j]; } }
  __syncthreads();
  int run = base[t];
  for (int i=i0;i<i1;++i){ int d = degcur[i]; row_ptr[i]=run; degcur[i]=run; run+=d; }
  if (t == 255) row_ptr[N_NODESC] = E_TOT;
}

__global__ void k_scatter(const int* __restrict__ ei, int* __restrict__ cursor,
                          int* __restrict__ col){
  int e = blockIdx.x*blockDim.x + threadIdx.x;
  if (e >= E_TOT) return;
  int s, d;
  if (e < N_EDGESC){ s = ei[e]; d = ei[N_EDGESC + e]; } else { s = e - N_EDGESC; d = s; }
  int pos = atomicAdd(&cursor[d], 1);
  col[pos] = s;
}

// ---------------- fused GEMM + attention logits ----------------
// out[M,144] = A[M,K] @ W[K,144] (+bias); optionally al_s/al_d = per-head dots.
// Block: 64 rows x 144 cols. 256 threads: cg = t>>4 (16 col-groups of 9 cols),
// rg = t&15 (16 row-groups of 4 rows). Per thread: 4x9 register tile.
// LDS: W chunk in padded groups of 12 (float4-aligned), A chunk transposed
// ([k][row], stride 68 so b128 stays 16B-aligned and banks rotate).
#define KC 36
#define SW_STRIDE 192   // 16 groups * 12
#define SAT_STRIDE 68
__global__ __launch_bounds__(256) void k_gemm_fused(
    const float* __restrict__ A, const float* __restrict__ W,
    const float* __restrict__ bias,
    const float* __restrict__ a_s, const float* __restrict__ a_d,
    float* __restrict__ out, float* __restrict__ al_s, float* __restrict__ al_d,
    int K, int H){
  extern __shared__ float smem[];
  float* sW  = smem;                 // KC * 192
  float* sAT = smem + KC*SW_STRIDE;  // KC * 68
  int t = threadIdx.x;
  int m0 = blockIdx.x * 64;
  int rg = t & 15, cg = t >> 4;
  int c0 = cg * 9;

  float acc[4][9];
  #pragma unroll
  for (int i=0;i<4;++i)
    #pragma unroll
    for (int j=0;j<9;++j) acc[i][j] = bias ? bias[c0+j] : 0.f;

  for (int k0 = 0; k0 < K; k0 += KC){
    int kc = min(KC, K - k0);
    __syncthreads();
    // stage W chunk (coalesced global read, regrouped into 12-wide groups)
    for (int i = t; i < kc*144; i += 256){
      int kk = i / 144, c = i - kk*144;
      int g = c / 9, j = c - g*9;
      sW[kk*SW_STRIDE + g*12 + j] = W[(size_t)(k0+kk)*144 + c];
    }
    // stage A^T chunk (coalesced global read along k, transposed LDS write)
    for (int i = t; i < 64*kc; i += 256){
      int r = i / kc, kk = i - r*kc;
      int m = m0 + r; if (m >= N_NODESC) m = N_NODESC - 1;
      sAT[kk*SAT_STRIDE + r] = A[(size_t)m*K + k0 + kk];
    }
    __syncthreads();
    for (int k = 0; k < kc; ++k){
      float4 a4 = *(const float4*)&sAT[k*SAT_STRIDE + rg*4];
      const float* wp = &sW[k*SW_STRIDE + cg*12];
      float4 w0 = *(const float4*)(wp);
      float4 w1 = *(const float4*)(wp+4);
      float  w8 = wp[8];
      float av[4] = {a4.x, a4.y, a4.z, a4.w};
      float wv[9] = {w0.x,w0.y,w0.z,w0.w,w1.x,w1.y,w1.z,w1.w,w8};
      #pragma unroll
      for (int i=0;i<4;++i)
        #pragma unroll
        for (int j=0;j<9;++j) acc[i][j] = fmaf(av[i], wv[j], acc[i][j]);
    }
  }

  // fused attention logits: al_s[m,h] = <hp[m,h,:], a_s[h,:]>
  if (H > 0){
    __syncthreads();           // done reading sW/sAT; reuse LDS
    float* sRs = smem;         // 64 x 17 (padded)
    float* sRd = smem + 64*17;
    float ps[4], pd[4];
    #pragma unroll
    for (int i=0;i<4;++i){ ps[i]=0.f; pd[i]=0.f; }
    #pragma unroll
    for (int j=0;j<9;++j){
      float asj = a_s[c0+j], adj = a_d[c0+j];
      #pragma unroll
      for (int i=0;i<4;++i){ ps[i] = fmaf(acc[i][j], asj, ps[i]); pd[i] = fmaf(acc[i][j], adj, pd[i]); }
    }
    #pragma unroll
    for (int i=0;i<4;++i){
      sRs[(rg*4+i)*17 + cg] = ps[i];
      sRd[(rg*4+i)*17 + cg] = pd[i];
    }
    __syncthreads();
    int G = 16 / H;
    for (int idx = t; idx < 64*H; idx += 256){
      int r = idx / H, h = idx - r*H;
      float ss = 0.f, sd = 0.f;
      for (int g2 = h*G; g2 < (h+1)*G; ++g2){ ss += sRs[r*17+g2]; sd += sRd[r*17+g2]; }
      int m = m0 + r;
      if (m < N_NODESC){ al_s[m*H+h] = ss; al_d[m*H+h] = sd; }
    }
  }

  // store
  #pragma unroll
  for (int i=0;i<4;++i){
    int m = m0 + rg*4 + i;
    if (m < N_NODESC){
      float* o = out + (size_t)m*DIM + c0;
      #pragma unroll
      for (int j=0;j<9;++j) o[j] = acc[i][j];
    }
  }
}

// ---------------- per-node softmax-attention aggregation (+bias+relu) ----------------
__global__ __launch_bounds__(192) void k_aggregate(
    const float* __restrict__ hp, const float* __restrict__ al_s,
    const float* __restrict__ al_d, const int* __restrict__ row_ptr,
    const int* __restrict__ col, const float* __restrict__ bias,
    float* __restrict__ out, int H, int C){
  int n = blockIdx.x;
  int t = threadIdx.x;
  __shared__ float s_max[8];
  __shared__ float red[64*8];
  int p0 = row_ptr[n], p1 = row_ptr[n+1];
  // phase 1: per-head max over incoming edges (64 threads)
  if (t < 64){
    float mx[8];
    for (int h=0;h<H;++h) mx[h] = -3.4e38f;
    for (int e = p0 + t; e < p1; e += 64){
      int s = col[e];
      for (int h=0;h<H;++h){
        float sc = lrelu(al_s[s*H+h] + al_d[n*H+h]);
        mx[h] = fmaxf(mx[h], sc);
      }
    }
    for (int h=0;h<H;++h) red[h*64+t] = mx[h];
  }
  __syncthreads();
  if (t < H){
    float m = red[t*64];
    for (int j=1;j<64;++j) m = fmaxf(m, red[t*64+j]);
    s_max[t] = m;
  }
  __syncthreads();
  // phase 2: one thread per output channel; den computed redundantly per channel
  if (t < DIM){
    int h = t / C;
    float ald = al_d[n*H+h];
    float m = s_max[h];
    float acc = 0.f, den = 0.f;
    for (int e=p0; e<p1; ++e){
      int s = col[e];
      float sc = lrelu(al_s[s*H+h] + ald);
      float ex = __expf(sc - m);
      den += ex;
      acc = fmaf(ex, hp[(size_t)s*DIM + t], acc);
    }
    float v = acc/(den + 1e-16f) + bias[t];
    out[(size_t)n*DIM + t] = fmaxf(v, 0.f);   // fused ReLU
  }
}

// ---------------- batchnorm over nodes ----------------
__global__ __launch_bounds__(256) void k_bnstats(const float* __restrict__ h,
                                                 float* __restrict__ sums){
  __shared__ float ls[2*DIM];
  int t = threadIdx.x;
  for (int i=t;i<2*DIM;i+=256) ls[i] = 0.f;
  __syncthreads();
  const long total = (long)N_NODESC*DIM;
  long per = (total + gridDim.x - 1)/gridDim.x;
  long i0 = (long)blockIdx.x*per, i1 = min(total, i0+per);
  for (long i = i0 + t; i < i1; i += 256){
    float v = h[i]; int c = (int)(i % DIM);
    atomicAdd(&ls[c], v);
    atomicAdd(&ls[DIM+c], v*v);
  }
  __syncthreads();
  for (int i=t;i<2*DIM;i+=256) atomicAdd(&sums[i], ls[i]);
}

__global__ void k_bnapply(float* __restrict__ h, const float* __restrict__ sums,
                          const float* __restrict__ gam, const float* __restrict__ bet){
  long i = (long)blockIdx.x*blockDim.x + threadIdx.x;
  const long total = (long)N_NODESC*DIM;
  if (i >= total) return;
  int c = (int)(i % DIM);
  float mu  = sums[c] * (1.f/N_NODESC);
  float var = sums[DIM+c] * (1.f/N_NODESC) - mu*mu;
  float inv = rsqrtf(var + EPSV);
  h[i] = fmaf((h[i]-mu)*inv, gam[c], bet[c]);
}

// ---------------- per-graph mean pool (batch is sorted) ----------------
__device__ int lbound(const int* a, int n, int v){
  int lo = 0, hi = n;
  while (lo < hi){ int m = (lo+hi) >> 1; if (a[m] < v) lo = m+1; else hi = m; }
  return lo;
}

__global__ __launch_bounds__(192) void k_pool(const float* __restrict__ h,
    const int* __restrict__ batch, float* __restrict__ sums, int* __restrict__ cnts){
  int g = blockIdx.x & 63, part = blockIdx.x >> 6;     // 8 parts per graph
  __shared__ int sb[2];
  if (threadIdx.x == 0){ sb[0] = lbound(batch, N_NODESC, g); sb[1] = lbound(batch, N_NODESC, g+1); }
  __syncthreads();
  int lo = sb[0], hi = sb[1];
  int t = threadIdx.x;
  if (t < DIM){
    float acc = 0.f;
    for (int n = lo + part; n < hi; n += 8) acc += h[(size_t)n*DIM + t];
    atomicAdd(&sums[g*DIM + t], acc);
  }
  if (t == 0 && part == 0) cnts[g] = hi - lo;
}

// ---------------- MLP head: 64x144 -> 72 -> 36 -> 112, BN+ReLU between ----------------
__global__ __launch_bounds__(256) void k_mlp(const float* __restrict__ sums,
    const int* __restrict__ cnts,
    const float* __restrict__ M1, const float* __restrict__ bm1,
    const float* __restrict__ gm1, const float* __restrict__ bb1,
    const float* __restrict__ M2, const float* __restrict__ bm2,
    const float* __restrict__ gm2, const float* __restrict__ bb2,
    const float* __restrict__ M3, const float* __restrict__ bm3,
    float* __restrict__ out){
  __shared__ float sg[64*144];
  __shared__ float s1[64*72];
  __shared__ float s2[64*36];
  __shared__ float stat[144];
  int t = threadIdx.x;
  for (int i=t; i<64*144; i+=256){ int g=i/144; float c=(float)max(cnts[g],1); sg[i]=sums[i]/c; }
  __syncthreads();
  for (int i=t; i<64*72; i+=256){
    int r=i/72, c=i-r*72; float a=bm1[c];
    for (int k=0;k<144;++k) a = fmaf(sg[r*144+k], M1[k*72+c], a);
    s1[i]=a;
  }
  __syncthreads();
  if (t < 72){
    float s=0.f,q=0.f;
    for (int r=0;r<64;++r){ float v=s1[r*72+t]; s+=v; q+=v*v; }
    float mu=s*(1.f/64.f); float var=q*(1.f/64.f)-mu*mu;
    stat[t]=mu; stat[72+t]=rsqrtf(var+EPSV);
  }
  __syncthreads();
  for (int i=t; i<64*72; i+=256){
    int c=i%72; float v=fmaf((s1[i]-stat[c])*stat[72+c], gm1[c], bb1[c]); s1[i]=fmaxf(v,0.f);
  }
  __syncthreads();
  for (int i=t; i<64*36; i+=256){
    int r=i/36, c=i-r*36; float a=bm2[c];
    for (int k=0;k<72;++k) a = fmaf(s1[r*72+k], M2[k*36+c], a);
    s2[i]=a;
  }
  __syncthreads();
  if (t < 36){
    float s=0.f,q=0.f;
    for (int r=0;r<64;++r){ float v=s2[r*36+t]; s+=v; q+=v*v; }
    float mu=s*(1.f/64.f); float var=q*(1.f/64.f)-mu*mu;
    stat[t]=mu; stat[36+t]=rsqrtf(var+EPSV);
  }
  __syncthreads();
  for (int i=t; i<64*36; i+=256){
    int c=i%36; float v=fmaf((s2[i]-stat[c])*stat[36+c], gm2[c], bb2[c]); s2[i]=fmaxf(v,0.f);
  }
  __syncthreads();
  for (int i=t; i<64*112; i+=256){
    int r=i/112, c=i-r*112; float a=bm3[c];
    for (int k=0;k<36;++k) a = fmaf(s2[r*36+k], M3[k*112+c], a);
    out[i]=a;
  }
}

extern "C" void kernel_launch(void* const* d_in, const int* in_sizes, int n_in,
                              void* d_out, int out_size, void* d_ws, size_t ws_size,
                              hipStream_t stream){
  const float* x    = (const float*)d_in[0];
  const int*   ei   = (const int*)d_in[1];
  const int*   batch= (const int*)d_in[2];
  const float* We   = (const float*)d_in[3];
  const float* be   = (const float*)d_in[4];
  const float* Wg   = (const float*)d_in[5];
  const float* a_sg = (const float*)d_in[6];
  const float* a_dg = (const float*)d_in[7];
  const float* bg   = (const float*)d_in[8];
  const float* gam  = (const float*)d_in[9];
  const float* bet  = (const float*)d_in[10];
  const float* W3   = (const float*)d_in[11];
  const float* a_s3 = (const float*)d_in[12];
  const float* a_d3 = (const float*)d_in[13];
  const float* b3   = (const float*)d_in[14];
  const float* gam3 = (const float*)d_in[15];
  const float* bet3 = (const float*)d_in[16];
  const float* M1   = (const float*)d_in[17];
  const float* bm1  = (const float*)d_in[18];
  const float* gm1  = (const float*)d_in[19];
  const float* bb1  = (const float*)d_in[20];
  const float* M2   = (const float*)d_in[21];
  const float* bm2  = (const float*)d_in[22];
  const float* gm2  = (const float*)d_in[23];
  const float* bb2  = (const float*)d_in[24];
  const float* M3   = (const float*)d_in[25];
  const float* bm3  = (const float*)d_in[26];
  float* out = (float*)d_out;

  char* ws = (char*)d_ws;
  size_t off = 0;
  auto alloc = [&](size_t bytes)->char*{
    char* p = ws + off; off += (bytes + 255) & ~(size_t)255; return p;
  };
  float* hA     = (float*)alloc((size_t)N_NODESC*DIM*4);
  float* hp     = (float*)alloc((size_t)N_NODESC*DIM*4);
  float* al_s   = (float*)alloc((size_t)N_NODESC*8*4);
  float* al_d   = (float*)alloc((size_t)N_NODESC*8*4);
  int* row_ptr  = (int*)alloc((size_t)(N_NODESC+1)*4);
  int* cursor   = (int*)alloc((size_t)N_NODESC*4);
  int* col      = (int*)alloc((size_t)E_TOT*4);
  float* bns    = (float*)alloc(2*DIM*4);
  float* psum   = (float*)alloc((size_t)NGRAPH*DIM*4);
  int* pcnt     = (int*)alloc(NGRAPH*4);
  (void)ws_size; (void)n_in; (void)in_sizes; (void)out_size;

  const int GEMM_GRID = (N_NODESC + 63)/64;                  // 782
  const size_t GEMM_LDS = (KC*SW_STRIDE + KC*SAT_STRIDE)*4;  // 37440 B

  // CSR build (same graph reused by all 4 GAT layers)
  hipMemsetAsync(cursor, 0, (size_t)N_NODESC*4, stream);
  k_count<<<(E_TOT+255)/256, 256, 0, stream>>>(ei, cursor);
  k_scan<<<1, 256, 0, stream>>>(cursor, row_ptr);
  k_scatter<<<(E_TOT+255)/256, 256, 0, stream>>>(ei, cursor, col);

  // embed: hA = x @ We + be (no attn epilogue)
  k_gemm_fused<<<GEMM_GRID, 256, GEMM_LDS, stream>>>(
      x, We, be, nullptr, nullptr, hA, nullptr, nullptr, 128, 0);

  for (int L=0; L<4; ++L){
    const float* W  = (L<3) ? (Wg  + (size_t)L*DIM*DIM) : W3;
    const float* as = (L<3) ? (a_sg + (size_t)L*8*18)   : a_s3;
    const float* ad = (L<3) ? (a_dg + (size_t)L*8*18)   : a_d3;
    const float* bb = (L<3) ? (bg  + L*DIM) : b3;
    const float* gm = (L<3) ? (gam + L*DIM) : gam3;
    const float* bt = (L<3) ? (bet + L*DIM) : bet3;
    int H = (L<3) ? 8 : 1;
    int C = (L<3) ? 18 : 144;
    k_gemm_fused<<<GEMM_GRID, 256, GEMM_LDS, stream>>>(
        hA, W, nullptr, as, ad, hp, al_s, al_d, DIM, H);
    k_aggregate<<<N_NODESC, 192, 0, stream>>>(hp, al_s, al_d, row_ptr, col, bb, hA, H, C);
    hipMemsetAsync(bns, 0, 2*DIM*4, stream);
    k_bnstats<<<256, 256, 0, stream>>>(hA, bns);
    k_bnapply<<<((size_t)N_NODESC*DIM+255)/256, 256, 0, stream>>>(hA, bns, gm, bt);
  }

  hipMemsetAsync(psum, 0, (size_t)NGRAPH*DIM*4, stream);
  k_pool<<<NGRAPH*8, 192, 0, stream>>>(hA, batch, psum, pcnt);
  k_mlp<<<1, 256, 0, stream>>>(psum, pcnt, M1,bm1,gm1,bb1, M2,bm2,gm2,bb2, M3,bm3, out);
}

// Round 3
// 1289.438 us; speedup vs baseline: 1.9380x; 1.3495x over previous
//
#include <hip/hip_runtime.h>
#include <cstdint>

#define N_NODESC 50000
#define N_EDGESC 500000
#define E_TOT    550000
#define DIM      144
#define NGRAPH   64
#define EPSV     1e-5f

__device__ __forceinline__ float lrelu(float x){ return x > 0.f ? x : 0.2f*x; }

// ---------------- CSR build (by dst, self-loops appended) ----------------
__global__ void k_count(const int* __restrict__ ei, int* __restrict__ deg){
  int e = blockIdx.x*blockDim.x + threadIdx.x;
  if (e >= E_TOT) return;
  int d = (e < N_EDGESC) ? ei[N_EDGESC + e] : (e - N_EDGESC);
  atomicAdd(&deg[d], 1);
}

__global__ void k_scan(int* __restrict__ degcur, int* __restrict__ row_ptr){
  __shared__ int part[256];
  __shared__ int base[256];
  int t = threadIdx.x;
  const int CH = (N_NODESC + 255)/256;
  int i0 = t*CH, i1 = min(N_NODESC, i0+CH);
  int s = 0;
  for (int i=i0;i<i1;++i) s += degcur[i];
  part[t] = s;
  __syncthreads();
  if (t == 0){ int run = 0; for (int j=0;j<256;++j){ base[j]=run; run+=part[j]; } }
  __syncthreads();
  int run = base[t];
  for (int i=i0;i<i1;++i){ int d = degcur[i]; row_ptr[i]=run; degcur[i]=run; run+=d; }
  if (t == 255) row_ptr[N_NODESC] = E_TOT;
}

__global__ void k_scatter(const int* __restrict__ ei, int* __restrict__ cursor,
                          int* __restrict__ col){
  int e = blockIdx.x*blockDim.x + threadIdx.x;
  if (e >= E_TOT) return;
  int s, d;
  if (e < N_EDGESC){ s = ei[e]; d = ei[N_EDGESC + e]; } else { s = e - N_EDGESC; d = s; }
  int pos = atomicAdd(&cursor[d], 1);
  col[pos] = s;
}

// ---------------- fused GEMM + BN-on-input + attention logits ----------------
// out[M,144] = BN(A)[M,K] @ W[K,144] (+bias); optionally al_s/al_d per-head dots.
// Block 64 rows x 144 cols, 256 threads, 4x9 register tile per thread.
#define KC 36
#define SW_STRIDE 192   // 16 groups * 12
#define SAT_STRIDE 68
__global__ __launch_bounds__(256) void k_gemm_fused(
    const float* __restrict__ A, const float* __restrict__ W,
    const float* __restrict__ bias,
    const float* __restrict__ a_s, const float* __restrict__ a_d,
    float* __restrict__ out, float* __restrict__ al_s, float* __restrict__ al_d,
    int K, int H,
    const float* __restrict__ bnsum, const float* __restrict__ bngam,
    const float* __restrict__ bnbet){
  extern __shared__ float smem[];
  float* sW  = smem;                 // KC * 192
  float* sAT = smem + KC*SW_STRIDE;  // KC * 68
  float* sBN = sAT + KC*SAT_STRIDE;  // 2*144 (scale, shift)
  int t = threadIdx.x;
  int m0 = blockIdx.x * 64;
  int rg = t & 15, cg = t >> 4;
  int c0 = cg * 9;

  if (bnsum){
    for (int i=t; i<K; i+=256){
      float mu  = bnsum[i] * (1.f/N_NODESC);
      float var = bnsum[K+i] * (1.f/N_NODESC) - mu*mu;
      float inv = rsqrtf(var + EPSV);
      float sc = inv * bngam[i];
      sBN[i] = sc; sBN[K+i] = bnbet[i] - mu*sc;
    }
    __syncthreads();
  }

  float acc[4][9];
  #pragma unroll
  for (int i=0;i<4;++i)
    #pragma unroll
    for (int j=0;j<9;++j) acc[i][j] = bias ? bias[c0+j] : 0.f;

  for (int k0 = 0; k0 < K; k0 += KC){
    int kc = min(KC, K - k0);
    __syncthreads();
    for (int i = t; i < kc*144; i += 256){
      int kk = i / 144, c = i - kk*144;
      int g = c / 9, j = c - g*9;
      sW[kk*SW_STRIDE + g*12 + j] = W[(size_t)(k0+kk)*144 + c];
    }
    for (int i = t; i < 64*kc; i += 256){
      int r = i / kc, kk = i - r*kc;
      int m = m0 + r; if (m >= N_NODESC) m = N_NODESC - 1;
      float v = A[(size_t)m*K + k0 + kk];
      if (bnsum) v = fmaf(v, sBN[k0+kk], sBN[K+k0+kk]);
      sAT[kk*SAT_STRIDE + r] = v;
    }
    __syncthreads();
    for (int k = 0; k < kc; ++k){
      float4 a4 = *(const float4*)&sAT[k*SAT_STRIDE + rg*4];
      const float* wp = &sW[k*SW_STRIDE + cg*12];
      float4 w0 = *(const float4*)(wp);
      float4 w1 = *(const float4*)(wp+4);
      float  w8 = wp[8];
      float av[4] = {a4.x, a4.y, a4.z, a4.w};
      float wv[9] = {w0.x,w0.y,w0.z,w0.w,w1.x,w1.y,w1.z,w1.w,w8};
      #pragma unroll
      for (int i=0;i<4;++i)
        #pragma unroll
        for (int j=0;j<9;++j) acc[i][j] = fmaf(av[i], wv[j], acc[i][j]);
    }
  }

  if (H > 0){
    __syncthreads();
    float* sRs = smem;
    float* sRd = smem + 64*17;
    float ps[4], pd[4];
    #pragma unroll
    for (int i=0;i<4;++i){ ps[i]=0.f; pd[i]=0.f; }
    #pragma unroll
    for (int j=0;j<9;++j){
      float asj = a_s[c0+j], adj = a_d[c0+j];
      #pragma unroll
      for (int i=0;i<4;++i){ ps[i] = fmaf(acc[i][j], asj, ps[i]); pd[i] = fmaf(acc[i][j], adj, pd[i]); }
    }
    #pragma unroll
    for (int i=0;i<4;++i){
      sRs[(rg*4+i)*17 + cg] = ps[i];
      sRd[(rg*4+i)*17 + cg] = pd[i];
    }
    __syncthreads();
    int G = 16 / H;
    for (int idx = t; idx < 64*H; idx += 256){
      int r = idx / H, h = idx - r*H;
      float ss = 0.f, sd = 0.f;
      for (int g2 = h*G; g2 < (h+1)*G; ++g2){ ss += sRs[r*17+g2]; sd += sRd[r*17+g2]; }
      int m = m0 + r;
      if (m < N_NODESC){ al_s[m*H+h] = ss; al_d[m*H+h] = sd; }
    }
  }

  #pragma unroll
  for (int i=0;i<4;++i){
    int m = m0 + rg*4 + i;
    if (m < N_NODESC){
      float* o = out + (size_t)m*DIM + c0;
      #pragma unroll
      for (int j=0;j<9;++j) o[j] = acc[i][j];
    }
  }
}

// ---------------- per-node softmax aggregation, online chunked ----------------
// One block = one dst node. Scores computed ONCE per (edge,head) into LDS;
// channel-threads then only do broadcast-LDS reads + the hp gather FMA.
#define ACH 64
__global__ __launch_bounds__(192) void k_aggregate(
    const float* __restrict__ hp, const float* __restrict__ al_s,
    const float* __restrict__ al_d, const int* __restrict__ row_ptr,
    const int* __restrict__ col, const float* __restrict__ bias,
    float* __restrict__ out, int H, int C){
  int n = blockIdx.x;
  int t = threadIdx.x;
  __shared__ int   s_src[ACH];
  __shared__ float s_ex[ACH*8];
  __shared__ float s_m[8], s_scale[8], s_den[8], s_ald[8];
  int p0 = row_ptr[n], p1 = row_ptr[n+1];
  if (t < H){ s_m[t] = -3.4e38f; s_den[t] = 0.f; s_ald[t] = al_d[n*H+t]; }
  int h = (t < DIM) ? (t / C) : 0;
  float acc = 0.f;

  for (int c0 = p0; c0 < p1; c0 += ACH){
    int cnt = min(ACH, p1 - c0);
    __syncthreads();                       // prev chunk fully consumed
    for (int i = t; i < cnt; i += 192) s_src[i] = col[c0 + i];
    __syncthreads();
    for (int i = t; i < cnt*H; i += 192){
      int e = i / H, hh = i - e*H;
      s_ex[e*H + hh] = lrelu(al_s[s_src[e]*H + hh] + s_ald[hh]);
    }
    __syncthreads();
    if (t < H){
      float m = s_m[t];
      for (int e = 0; e < cnt; ++e) m = fmaxf(m, s_ex[e*H + t]);
      s_scale[t] = __expf(s_m[t] - m);     // first chunk: exp(-inf)=0
      s_m[t] = m;
    }
    __syncthreads();
    for (int i = t; i < cnt*H; i += 192){
      int e = i / H, hh = i - e*H;
      s_ex[e*H + hh] = __expf(s_ex[e*H + hh] - s_m[hh]);
    }
    __syncthreads();
    if (t < H){
      float d = s_den[t] * s_scale[t];
      for (int e = 0; e < cnt; ++e) d += s_ex[e*H + t];
      s_den[t] = d;
    }
    if (t < DIM){
      acc *= s_scale[h];
      for (int e = 0; e < cnt; ++e){
        int s = s_src[e];
        acc = fmaf(s_ex[e*H + h], hp[(size_t)s*DIM + t], acc);
      }
    }
  }
  __syncthreads();
  if (t < DIM){
    float v = acc/(s_den[h] + 1e-16f) + bias[t];
    out[(size_t)n*DIM + t] = fmaxf(v, 0.f);   // fused ReLU
  }
}

// ---------------- batchnorm stats: register accumulate, coalesced ----------------
__global__ __launch_bounds__(192) void k_bnstats(const float* __restrict__ h,
                                                 float* __restrict__ sums){
  int t = threadIdx.x;
  if (t >= DIM) return;
  int rows = (N_NODESC + gridDim.x - 1)/gridDim.x;
  int n0 = blockIdx.x*rows, n1 = min(N_NODESC, n0+rows);
  float s = 0.f, q = 0.f;
  for (int n = n0; n < n1; ++n){
    float v = h[(size_t)n*DIM + t];
    s += v; q += v*v;
  }
  atomicAdd(&sums[t], s);
  atomicAdd(&sums[DIM+t], q);
}

// ---------------- per-graph mean pool (batch is sorted) ----------------
__device__ int lbound(const int* a, int n, int v){
  int lo = 0, hi = n;
  while (lo < hi){ int m = (lo+hi) >> 1; if (a[m] < v) lo = m+1; else hi = m; }
  return lo;
}

__global__ __launch_bounds__(192) void k_pool(const float* __restrict__ h,
    const int* __restrict__ batch, float* __restrict__ sums, int* __restrict__ cnts){
  int g = blockIdx.x & 63, part = blockIdx.x >> 6;     // 8 parts per graph
  __shared__ int sb[2];
  if (threadIdx.x == 0){ sb[0] = lbound(batch, N_NODESC, g); sb[1] = lbound(batch, N_NODESC, g+1); }
  __syncthreads();
  int lo = sb[0], hi = sb[1];
  int t = threadIdx.x;
  if (t < DIM){
    float acc = 0.f;
    for (int n = lo + part; n < hi; n += 8) acc += h[(size_t)n*DIM + t];
    atomicAdd(&sums[g*DIM + t], acc);
  }
  if (t == 0 && part == 0) cnts[g] = hi - lo;
}

// ---------------- MLP head (final BN fused into pooled-mean load) ----------------
__global__ __launch_bounds__(256) void k_mlp(const float* __restrict__ sums,
    const int* __restrict__ cnts,
    const float* __restrict__ bn3, const float* __restrict__ gam3,
    const float* __restrict__ bet3,
    const float* __restrict__ M1, const float* __restrict__ bm1,
    const float* __restrict__ gm1, const float* __restrict__ bb1,
    const float* __restrict__ M2, const float* __restrict__ bm2,
    const float* __restrict__ gm2, const float* __restrict__ bb2,
    const float* __restrict__ M3, const float* __restrict__ bm3,
    float* __restrict__ out){
  __shared__ float sg[64*144];
  __shared__ float s1[64*72];
  __shared__ float s2[64*36];
  __shared__ float stat[144];
  int t = threadIdx.x;
  for (int i=t; i<64*144; i+=256){
    int g=i/144, c=i-g*144;
    float cf=(float)max(cnts[g],1);
    float mu  = bn3[c]*(1.f/N_NODESC);
    float var = bn3[144+c]*(1.f/N_NODESC) - mu*mu;
    float inv = rsqrtf(var + EPSV);
    float sc = inv*gam3[c];
    sg[i] = (sums[i]/cf - mu)*sc + bet3[c];
  }
  __syncthreads();
  for (int i=t; i<64*72; i+=256){
    int r=i/72, c=i-r*72; float a=bm1[c];
    for (int k=0;k<144;++k) a = fmaf(sg[r*144+k], M1[k*72+c], a);
    s1[i]=a;
  }
  __syncthreads();
  if (t < 72){
    float s=0.f,q=0.f;
    for (int r=0;r<64;++r){ float v=s1[r*72+t]; s+=v; q+=v*v; }
    float mu=s*(1.f/64.f); float var=q*(1.f/64.f)-mu*mu;
    stat[t]=mu; stat[72+t]=rsqrtf(var+EPSV);
  }
  __syncthreads();
  for (int i=t; i<64*72; i+=256){
    int c=i%72; float v=fmaf((s1[i]-stat[c])*stat[72+c], gm1[c], bb1[c]); s1[i]=fmaxf(v,0.f);
  }
  __syncthreads();
  for (int i=t; i<64*36; i+=256){
    int r=i/36, c=i-r*36; float a=bm2[c];
    for (int k=0;k<72;++k) a = fmaf(s1[r*72+k], M2[k*36+c], a);
    s2[i]=a;
  }
  __syncthreads();
  if (t < 36){
    float s=0.f,q=0.f;
    for (int r=0;r<64;++r){ float v=s2[r*36+t]; s+=v; q+=v*v; }
    float mu=s*(1.f/64.f); float var=q*(1.f/64.f)-mu*mu;
    stat[t]=mu; stat[36+t]=rsqrtf(var+EPSV);
  }
  __syncthreads();
  for (int i=t; i<64*36; i+=256){
    int c=i%36; float v=fmaf((s2[i]-stat[c])*stat[36+c], gm2[c], bb2[c]); s2[i]=fmaxf(v,0.f);
  }
  __syncthreads();
  for (int i=t; i<64*112; i+=256){
    int r=i/112, c=i-r*112; float a=bm3[c];
    for (int k=0;k<36;++k) a = fmaf(s2[r*36+k], M3[k*112+c], a);
    out[i]=a;
  }
}

extern "C" void kernel_launch(void* const* d_in, const int* in_sizes, int n_in,
                              void* d_out, int out_size, void* d_ws, size_t ws_size,
                              hipStream_t stream){
  const float* x    = (const float*)d_in[0];
  const int*   ei   = (const int*)d_in[1];
  const int*   batch= (const int*)d_in[2];
  const float* We   = (const float*)d_in[3];
  const float* be   = (const float*)d_in[4];
  const float* Wg   = (const float*)d_in[5];
  const float* a_sg = (const float*)d_in[6];
  const float* a_dg = (const float*)d_in[7];
  const float* bg   = (const float*)d_in[8];
  const float* gam  = (const float*)d_in[9];
  const float* bet  = (const float*)d_in[10];
  const float* W3   = (const float*)d_in[11];
  const float* a_s3 = (const float*)d_in[12];
  const float* a_d3 = (const float*)d_in[13];
  const float* b3   = (const float*)d_in[14];
  const float* gam3 = (const float*)d_in[15];
  const float* bet3 = (const float*)d_in[16];
  const float* M1   = (const float*)d_in[17];
  const float* bm1  = (const float*)d_in[18];
  const float* gm1  = (const float*)d_in[19];
  const float* bb1  = (const float*)d_in[20];
  const float* M2   = (const float*)d_in[21];
  const float* bm2  = (const float*)d_in[22];
  const float* gm2  = (const float*)d_in[23];
  const float* bb2  = (const float*)d_in[24];
  const float* M3   = (const float*)d_in[25];
  const float* bm3  = (const float*)d_in[26];
  float* out = (float*)d_out;

  char* ws = (char*)d_ws;
  size_t off = 0;
  auto alloc = [&](size_t bytes)->char*{
    char* p = ws + off; off += (bytes + 255) & ~(size_t)255; return p;
  };
  float* hA     = (float*)alloc((size_t)N_NODESC*DIM*4);
  float* hp     = (float*)alloc((size_t)N_NODESC*DIM*4);
  float* al_s   = (float*)alloc((size_t)N_NODESC*8*4);
  float* al_d   = (float*)alloc((size_t)N_NODESC*8*4);
  int* row_ptr  = (int*)alloc((size_t)(N_NODESC+1)*4);
  int* cursor   = (int*)alloc((size_t)N_NODESC*4);
  int* col      = (int*)alloc((size_t)E_TOT*4);
  float* bns4   = (float*)alloc(4*2*DIM*4);   // per-layer BN stats
  float* psum   = (float*)alloc((size_t)NGRAPH*DIM*4);
  int* pcnt     = (int*)alloc(NGRAPH*4);
  (void)ws_size; (void)n_in; (void)in_sizes; (void)out_size;

  const int GEMM_GRID = (N_NODESC + 63)/64;                        // 782
  const size_t GEMM_LDS = (KC*SW_STRIDE + KC*SAT_STRIDE + 2*DIM)*4; // 38592 B

  // CSR build (same graph reused by all 4 GAT layers)
  hipMemsetAsync(cursor, 0, (size_t)N_NODESC*4, stream);
  hipMemsetAsync(bns4, 0, 4*2*DIM*4, stream);
  k_count<<<(E_TOT+255)/256, 256, 0, stream>>>(ei, cursor);
  k_scan<<<1, 256, 0, stream>>>(cursor, row_ptr);
  k_scatter<<<(E_TOT+255)/256, 256, 0, stream>>>(ei, cursor, col);

  // embed: hA = x @ We + be
  k_gemm_fused<<<GEMM_GRID, 256, GEMM_LDS, stream>>>(
      x, We, be, nullptr, nullptr, hA, nullptr, nullptr, 128, 0,
      nullptr, nullptr, nullptr);

  for (int L=0; L<4; ++L){
    const float* W  = (L<3) ? (Wg  + (size_t)L*DIM*DIM) : W3;
    const float* as = (L<3) ? (a_sg + (size_t)L*8*18)   : a_s3;
    const float* ad = (L<3) ? (a_dg + (size_t)L*8*18)   : a_d3;
    const float* bb = (L<3) ? (bg  + L*DIM) : b3;
    int H = (L<3) ? 8 : 1;
    int C = (L<3) ? 18 : 144;
    // BN of the PREVIOUS layer's output is applied while staging A
    const float* bnp = (L==0) ? nullptr : bns4 + (size_t)(L-1)*2*DIM;
    const float* gmp = (L==0) ? nullptr : gam + (size_t)(L-1)*DIM;
    const float* btp = (L==0) ? nullptr : bet + (size_t)(L-1)*DIM;
    k_gemm_fused<<<GEMM_GRID, 256, GEMM_LDS, stream>>>(
        hA, W, nullptr, as, ad, hp, al_s, al_d, DIM, H, bnp, gmp, btp);
    k_aggregate<<<N_NODESC, 192, 0, stream>>>(hp, al_s, al_d, row_ptr, col, bb, hA, H, C);
    k_bnstats<<<256, 192, 0, stream>>>(hA, bns4 + (size_t)L*2*DIM);
  }

  hipMemsetAsync(psum, 0, (size_t)NGRAPH*DIM*4, stream);
  k_pool<<<NGRAPH*8, 192, 0, stream>>>(hA, batch, psum, pcnt);
  k_mlp<<<1, 256, 0, stream>>>(psum, pcnt, bns4 + 3*2*DIM, gam3, bet3,
                               M1,bm1,gm1,bb1, M2,bm2,gm2,bb2, M3,bm3, out);
}

// Round 4
// 1175.651 us; speedup vs baseline: 2.1255x; 1.0968x over previous
//
#include <hip/hip_runtime.h>
#include <cstdint>

#define N_NODESC 50000
#define N_EDGESC 500000
#define E_TOT    550000
#define DIM      144
#define NGRAPH   64
#define EPSV     1e-5f
#define SCAN_NB  ((N_NODESC + 511)/512)   // 98 blocks of 512 elements

__device__ __forceinline__ float lrelu(float x){ return x > 0.f ? x : 0.2f*x; }

// ---------------- CSR build (by dst, self-loops appended) ----------------
__global__ void k_count(const int* __restrict__ ei, int* __restrict__ deg){
  int e = blockIdx.x*blockDim.x + threadIdx.x;
  if (e >= E_TOT) return;
  int d = (e < N_EDGESC) ? ei[N_EDGESC + e] : (e - N_EDGESC);
  atomicAdd(&deg[d], 1);
}

// parallel scan, stage 1: per-block (512 elems) exclusive scan + block total
__global__ __launch_bounds__(256) void k_scan1(const int* __restrict__ deg,
    int* __restrict__ scanned, int* __restrict__ bsum){
  __shared__ int ls[256];
  int b = blockIdx.x, t = threadIdx.x;
  int i0 = b*512 + 2*t;
  int e0 = (i0   < N_NODESC) ? deg[i0]   : 0;
  int e1 = (i0+1 < N_NODESC) ? deg[i0+1] : 0;
  int s = e0 + e1;
  ls[t] = s;
  __syncthreads();
  #pragma unroll
  for (int ofs=1; ofs<256; ofs<<=1){
    int v = (t >= ofs) ? ls[t-ofs] : 0;
    __syncthreads();
    ls[t] += v;
    __syncthreads();
  }
  int excl = ls[t] - s;
  if (i0   < N_NODESC) scanned[i0]   = excl;
  if (i0+1 < N_NODESC) scanned[i0+1] = excl + e0;
  if (t == 255) bsum[b] = ls[255];
}

// stage 2: exclusive scan of block totals (98 <= 128)
__global__ void k_scan2(int* __restrict__ bsum){
  __shared__ int ls[128];
  int t = threadIdx.x;
  int v = (t < SCAN_NB) ? bsum[t] : 0;
  ls[t] = v;
  __syncthreads();
  #pragma unroll
  for (int ofs=1; ofs<128; ofs<<=1){
    int u = (t >= ofs) ? ls[t-ofs] : 0;
    __syncthreads();
    ls[t] += u;
    __syncthreads();
  }
  if (t < SCAN_NB) bsum[t] = ls[t] - v;
}

// stage 3: add block offsets -> row_ptr + cursor
__global__ __launch_bounds__(256) void k_scan3(const int* __restrict__ scanned,
    const int* __restrict__ bsum, int* __restrict__ row_ptr, int* __restrict__ cursor){
  int i = blockIdx.x*blockDim.x + threadIdx.x;
  if (i < N_NODESC){
    int v = scanned[i] + bsum[i >> 9];
    row_ptr[i] = v; cursor[i] = v;
  }
  if (i == 0) row_ptr[N_NODESC] = E_TOT;
}

__global__ void k_scatter(const int* __restrict__ ei, int* __restrict__ cursor,
                          int* __restrict__ col){
  int e = blockIdx.x*blockDim.x + threadIdx.x;
  if (e >= E_TOT) return;
  int s, d;
  if (e < N_EDGESC){ s = ei[e]; d = ei[N_EDGESC + e]; } else { s = e - N_EDGESC; d = s; }
  int pos = atomicAdd(&cursor[d], 1);
  col[pos] = s;
}

// ---------------- fused GEMM + BN-on-input + attention logits ----------------
// out[M,144] = BN(A)[M,K] @ W[K,144] (+bias); optionally al_s/al_d per-head dots.
// Block 64 rows x 144 cols, 256 threads, 4x9 register tile per thread.
#define KC 36
#define SW_STRIDE 192   // 16 groups * 12
#define SAT_STRIDE 68
__global__ __launch_bounds__(256) void k_gemm_fused(
    const float* __restrict__ A, const float* __restrict__ W,
    const float* __restrict__ bias,
    const float* __restrict__ a_s, const float* __restrict__ a_d,
    float* __restrict__ out, float* __restrict__ al_s, float* __restrict__ al_d,
    int K, int H,
    const float* __restrict__ bnsum, const float* __restrict__ bngam,
    const float* __restrict__ bnbet){
  extern __shared__ float smem[];
  float* sW  = smem;                 // KC * 192
  float* sAT = smem + KC*SW_STRIDE;  // KC * 68
  float* sBN = sAT + KC*SAT_STRIDE;  // 2*144 (scale, shift)
  int t = threadIdx.x;
  int m0 = blockIdx.x * 64;
  int rg = t & 15, cg = t >> 4;
  int c0 = cg * 9;

  if (bnsum){
    for (int i=t; i<K; i+=256){
      float mu  = bnsum[i] * (1.f/N_NODESC);
      float var = bnsum[K+i] * (1.f/N_NODESC) - mu*mu;
      float inv = rsqrtf(var + EPSV);
      float sc = inv * bngam[i];
      sBN[i] = sc; sBN[K+i] = bnbet[i] - mu*sc;
    }
    __syncthreads();
  }

  float acc[4][9];
  #pragma unroll
  for (int i=0;i<4;++i)
    #pragma unroll
    for (int j=0;j<9;++j) acc[i][j] = bias ? bias[c0+j] : 0.f;

  for (int k0 = 0; k0 < K; k0 += KC){
    int kc = min(KC, K - k0);
    __syncthreads();
    for (int i = t; i < kc*144; i += 256){
      int kk = i / 144, c = i - kk*144;
      int g = c / 9, j = c - g*9;
      sW[kk*SW_STRIDE + g*12 + j] = W[(size_t)(k0+kk)*144 + c];
    }
    for (int i = t; i < 64*kc; i += 256){
      int r = i / kc, kk = i - r*kc;
      int m = m0 + r; if (m >= N_NODESC) m = N_NODESC - 1;
      float v = A[(size_t)m*K + k0 + kk];
      if (bnsum) v = fmaf(v, sBN[k0+kk], sBN[K+k0+kk]);
      sAT[kk*SAT_STRIDE + r] = v;
    }
    __syncthreads();
    for (int k = 0; k < kc; ++k){
      float4 a4 = *(const float4*)&sAT[k*SAT_STRIDE + rg*4];
      const float* wp = &sW[k*SW_STRIDE + cg*12];
      float4 w0 = *(const float4*)(wp);
      float4 w1 = *(const float4*)(wp+4);
      float  w8 = wp[8];
      float av[4] = {a4.x, a4.y, a4.z, a4.w};
      float wv[9] = {w0.x,w0.y,w0.z,w0.w,w1.x,w1.y,w1.z,w1.w,w8};
      #pragma unroll
      for (int i=0;i<4;++i)
        #pragma unroll
        for (int j=0;j<9;++j) acc[i][j] = fmaf(av[i], wv[j], acc[i][j]);
    }
  }

  if (H > 0){
    __syncthreads();
    float* sRs = smem;
    float* sRd = smem + 64*17;
    float ps[4], pd[4];
    #pragma unroll
    for (int i=0;i<4;++i){ ps[i]=0.f; pd[i]=0.f; }
    #pragma unroll
    for (int j=0;j<9;++j){
      float asj = a_s[c0+j], adj = a_d[c0+j];
      #pragma unroll
      for (int i=0;i<4;++i){ ps[i] = fmaf(acc[i][j], asj, ps[i]); pd[i] = fmaf(acc[i][j], adj, pd[i]); }
    }
    #pragma unroll
    for (int i=0;i<4;++i){
      sRs[(rg*4+i)*17 + cg] = ps[i];
      sRd[(rg*4+i)*17 + cg] = pd[i];
    }
    __syncthreads();
    int G = 16 / H;
    for (int idx = t; idx < 64*H; idx += 256){
      int r = idx / H, h = idx - r*H;
      float ss = 0.f, sd = 0.f;
      for (int g2 = h*G; g2 < (h+1)*G; ++g2){ ss += sRs[r*17+g2]; sd += sRd[r*17+g2]; }
      int m = m0 + r;
      if (m < N_NODESC){ al_s[m*H+h] = ss; al_d[m*H+h] = sd; }
    }
  }

  #pragma unroll
  for (int i=0;i<4;++i){
    int m = m0 + rg*4 + i;
    if (m < N_NODESC){
      float* o = out + (size_t)m*DIM + c0;
      #pragma unroll
      for (int j=0;j<9;++j) o[j] = acc[i][j];
    }
  }
}

// ---------------- per-node softmax aggregation, online chunked ----------------
#define ACH 64
__global__ __launch_bounds__(192) void k_aggregate(
    const float* __restrict__ hp, const float* __restrict__ al_s,
    const float* __restrict__ al_d, const int* __restrict__ row_ptr,
    const int* __restrict__ col, const float* __restrict__ bias,
    float* __restrict__ out, int H, int C){
  int n = blockIdx.x;
  int t = threadIdx.x;
  __shared__ int   s_src[ACH];
  __shared__ float s_ex[ACH*8];
  __shared__ float s_m[8], s_scale[8], s_den[8], s_ald[8];
  int p0 = row_ptr[n], p1 = row_ptr[n+1];
  if (t < H){ s_m[t] = -3.4e38f; s_den[t] = 0.f; s_ald[t] = al_d[n*H+t]; }
  int h = (t < DIM) ? (t / C) : 0;
  float acc = 0.f;

  for (int c0 = p0; c0 < p1; c0 += ACH){
    int cnt = min(ACH, p1 - c0);
    __syncthreads();                       // prev chunk fully consumed
    for (int i = t; i < cnt; i += 192) s_src[i] = col[c0 + i];
    __syncthreads();
    for (int i = t; i < cnt*H; i += 192){
      int e = i / H, hh = i - e*H;
      s_ex[e*H + hh] = lrelu(al_s[s_src[e]*H + hh] + s_ald[hh]);
    }
    __syncthreads();
    if (t < H){
      float m = s_m[t];
      for (int e = 0; e < cnt; ++e) m = fmaxf(m, s_ex[e*H + t]);
      s_scale[t] = __expf(s_m[t] - m);     // first chunk: exp(-inf)=0
      s_m[t] = m;
    }
    __syncthreads();
    for (int i = t; i < cnt*H; i += 192){
      int e = i / H, hh = i - e*H;
      s_ex[e*H + hh] = __expf(s_ex[e*H + hh] - s_m[hh]);
    }
    __syncthreads();
    if (t < H){
      float d = s_den[t] * s_scale[t];
      for (int e = 0; e < cnt; ++e) d += s_ex[e*H + t];
      s_den[t] = d;
    }
    if (t < DIM){
      acc *= s_scale[h];
      for (int e = 0; e < cnt; ++e){
        int s = s_src[e];
        acc = fmaf(s_ex[e*H + h], hp[(size_t)s*DIM + t], acc);
      }
    }
  }
  __syncthreads();
  if (t < DIM){
    float v = acc/(s_den[h] + 1e-16f) + bias[t];
    out[(size_t)n*DIM + t] = fmaxf(v, 0.f);   // fused ReLU
  }
}

// ---------------- batchnorm stats: register accumulate, coalesced ----------------
__global__ __launch_bounds__(192) void k_bnstats(const float* __restrict__ h,
                                                 float* __restrict__ sums){
  int t = threadIdx.x;
  if (t >= DIM) return;
  int rows = (N_NODESC + gridDim.x - 1)/gridDim.x;
  int n0 = blockIdx.x*rows, n1 = min(N_NODESC, n0+rows);
  float s = 0.f, q = 0.f;
  for (int n = n0; n < n1; ++n){
    float v = h[(size_t)n*DIM + t];
    s += v; q += v*v;
  }
  atomicAdd(&sums[t], s);
  atomicAdd(&sums[DIM+t], q);
}

// ---------------- per-graph mean pool (batch is sorted) ----------------
__device__ int lbound(const int* a, int n, int v){
  int lo = 0, hi = n;
  while (lo < hi){ int m = (lo+hi) >> 1; if (a[m] < v) lo = m+1; else hi = m; }
  return lo;
}

__global__ __launch_bounds__(192) void k_pool(const float* __restrict__ h,
    const int* __restrict__ batch, float* __restrict__ sums, int* __restrict__ cnts){
  int g = blockIdx.x & 63, part = blockIdx.x >> 6;     // 8 parts per graph
  __shared__ int sb[2];
  if (threadIdx.x == 0){ sb[0] = lbound(batch, N_NODESC, g); sb[1] = lbound(batch, N_NODESC, g+1); }
  __syncthreads();
  int lo = sb[0], hi = sb[1];
  int t = threadIdx.x;
  if (t < DIM){
    float acc = 0.f;
    for (int n = lo + part; n < hi; n += 8) acc += h[(size_t)n*DIM + t];
    atomicAdd(&sums[g*DIM + t], acc);
  }
  if (t == 0 && part == 0) cnts[g] = hi - lo;
}

// ---------------- MLP head (final BN fused into pooled-mean load) ----------------
__global__ __launch_bounds__(256) void k_mlp(const float* __restrict__ sums,
    const int* __restrict__ cnts,
    const float* __restrict__ bn3, const float* __restrict__ gam3,
    const float* __restrict__ bet3,
    const float* __restrict__ M1, const float* __restrict__ bm1,
    const float* __restrict__ gm1, const float* __restrict__ bb1,
    const float* __restrict__ M2, const float* __restrict__ bm2,
    const float* __restrict__ gm2, const float* __restrict__ bb2,
    const float* __restrict__ M3, const float* __restrict__ bm3,
    float* __restrict__ out){
  __shared__ float sg[64*144];
  __shared__ float s1[64*72];
  __shared__ float s2[64*36];
  __shared__ float stat[144];
  int t = threadIdx.x;
  for (int i=t; i<64*144; i+=256){
    int g=i/144, c=i-g*144;
    float cf=(float)max(cnts[g],1);
    float mu  = bn3[c]*(1.f/N_NODESC);
    float var = bn3[144+c]*(1.f/N_NODESC) - mu*mu;
    float inv = rsqrtf(var + EPSV);
    float sc = inv*gam3[c];
    sg[i] = (sums[i]/cf - mu)*sc + bet3[c];
  }
  __syncthreads();
  for (int i=t; i<64*72; i+=256){
    int r=i/72, c=i-r*72; float a=bm1[c];
    for (int k=0;k<144;++k) a = fmaf(sg[r*144+k], M1[k*72+c], a);
    s1[i]=a;
  }
  __syncthreads();
  if (t < 72){
    float s=0.f,q=0.f;
    for (int r=0;r<64;++r){ float v=s1[r*72+t]; s+=v; q+=v*v; }
    float mu=s*(1.f/64.f); float var=q*(1.f/64.f)-mu*mu;
    stat[t]=mu; stat[72+t]=rsqrtf(var+EPSV);
  }
  __syncthreads();
  for (int i=t; i<64*72; i+=256){
    int c=i%72; float v=fmaf((s1[i]-stat[c])*stat[72+c], gm1[c], bb1[c]); s1[i]=fmaxf(v,0.f);
  }
  __syncthreads();
  for (int i=t; i<64*36; i+=256){
    int r=i/36, c=i-r*36; float a=bm2[c];
    for (int k=0;k<72;++k) a = fmaf(s1[r*72+k], M2[k*36+c], a);
    s2[i]=a;
  }
  __syncthreads();
  if (t < 36){
    float s=0.f,q=0.f;
    for (int r=0;r<64;++r){ float v=s2[r*36+t]; s+=v; q+=v*v; }
    float mu=s*(1.f/64.f); float var=q*(1.f/64.f)-mu*mu;
    stat[t]=mu; stat[36+t]=rsqrtf(var+EPSV);
  }
  __syncthreads();
  for (int i=t; i<64*36; i+=256){
    int c=i%36; float v=fmaf((s2[i]-stat[c])*stat[36+c], gm2[c], bb2[c]); s2[i]=fmaxf(v,0.f);
  }
  __syncthreads();
  for (int i=t; i<64*112; i+=256){
    int r=i/112, c=i-r*112; float a=bm3[c];
    for (int k=0;k<36;++k) a = fmaf(s2[r*36+k], M3[k*112+c], a);
    out[i]=a;
  }
}

extern "C" void kernel_launch(void* const* d_in, const int* in_sizes, int n_in,
                              void* d_out, int out_size, void* d_ws, size_t ws_size,
                              hipStream_t stream){
  const float* x    = (const float*)d_in[0];
  const int*   ei   = (const int*)d_in[1];
  const int*   batch= (const int*)d_in[2];
  const float* We   = (const float*)d_in[3];
  const float* be   = (const float*)d_in[4];
  const float* Wg   = (const float*)d_in[5];
  const float* a_sg = (const float*)d_in[6];
  const float* a_dg = (const float*)d_in[7];
  const float* bg   = (const float*)d_in[8];
  const float* gam  = (const float*)d_in[9];
  const float* bet  = (const float*)d_in[10];
  const float* W3   = (const float*)d_in[11];
  const float* a_s3 = (const float*)d_in[12];
  const float* a_d3 = (const float*)d_in[13];
  const float* b3   = (const float*)d_in[14];
  const float* gam3 = (const float*)d_in[15];
  const float* bet3 = (const float*)d_in[16];
  const float* M1   = (const float*)d_in[17];
  const float* bm1  = (const float*)d_in[18];
  const float* gm1  = (const float*)d_in[19];
  const float* bb1  = (const float*)d_in[20];
  const float* M2   = (const float*)d_in[21];
  const float* bm2  = (const float*)d_in[22];
  const float* gm2  = (const float*)d_in[23];
  const float* bb2  = (const float*)d_in[24];
  const float* M3   = (const float*)d_in[25];
  const float* bm3  = (const float*)d_in[26];
  float* out = (float*)d_out;

  char* ws = (char*)d_ws;
  size_t off = 0;
  auto alloc = [&](size_t bytes)->char*{
    char* p = ws + off; off += (bytes + 255) & ~(size_t)255; return p;
  };
  float* hA     = (float*)alloc((size_t)N_NODESC*DIM*4);
  float* hp     = (float*)alloc((size_t)N_NODESC*DIM*4);
  float* al_s   = (float*)alloc((size_t)N_NODESC*8*4);
  float* al_d   = (float*)alloc((size_t)N_NODESC*8*4);
  int* row_ptr  = (int*)alloc((size_t)(N_NODESC+1)*4);
  int* deg      = (int*)alloc((size_t)N_NODESC*4);
  int* cursor   = (int*)alloc((size_t)N_NODESC*4);
  int* scanned  = (int*)alloc((size_t)N_NODESC*4);
  int* bsum     = (int*)alloc((size_t)SCAN_NB*4);
  int* col      = (int*)alloc((size_t)E_TOT*4);
  float* bns4   = (float*)alloc(4*2*DIM*4);   // per-layer BN stats
  float* psum   = (float*)alloc((size_t)NGRAPH*DIM*4);
  int* pcnt     = (int*)alloc(NGRAPH*4);
  (void)ws_size; (void)n_in; (void)in_sizes; (void)out_size;

  const int GEMM_GRID = (N_NODESC + 63)/64;                        // 782
  const size_t GEMM_LDS = (KC*SW_STRIDE + KC*SAT_STRIDE + 2*DIM)*4; // 38592 B

  // CSR build (same graph reused by all 4 GAT layers) — parallel scan
  hipMemsetAsync(deg, 0, (size_t)N_NODESC*4, stream);
  hipMemsetAsync(bns4, 0, 4*2*DIM*4, stream);
  k_count<<<(E_TOT+255)/256, 256, 0, stream>>>(ei, deg);
  k_scan1<<<SCAN_NB, 256, 0, stream>>>(deg, scanned, bsum);
  k_scan2<<<1, 128, 0, stream>>>(bsum);
  k_scan3<<<(N_NODESC+255)/256, 256, 0, stream>>>(scanned, bsum, row_ptr, cursor);
  k_scatter<<<(E_TOT+255)/256, 256, 0, stream>>>(ei, cursor, col);

  // embed: hA = x @ We + be
  k_gemm_fused<<<GEMM_GRID, 256, GEMM_LDS, stream>>>(
      x, We, be, nullptr, nullptr, hA, nullptr, nullptr, 128, 0,
      nullptr, nullptr, nullptr);

  for (int L=0; L<4; ++L){
    const float* W  = (L<3) ? (Wg  + (size_t)L*DIM*DIM) : W3;
    const float* as = (L<3) ? (a_sg + (size_t)L*8*18)   : a_s3;
    const float* ad = (L<3) ? (a_dg + (size_t)L*8*18)   : a_d3;
    const float* bb = (L<3) ? (bg  + L*DIM) : b3;
    int H = (L<3) ? 8 : 1;
    int C = (L<3) ? 18 : 144;
    // BN of the PREVIOUS layer's output is applied while staging A
    const float* bnp = (L==0) ? nullptr : bns4 + (size_t)(L-1)*2*DIM;
    const float* gmp = (L==0) ? nullptr : gam + (size_t)(L-1)*DIM;
    const float* btp = (L==0) ? nullptr : bet + (size_t)(L-1)*DIM;
    k_gemm_fused<<<GEMM_GRID, 256, GEMM_LDS, stream>>>(
        hA, W, nullptr, as, ad, hp, al_s, al_d, DIM, H, bnp, gmp, btp);
    k_aggregate<<<N_NODESC, 192, 0, stream>>>(hp, al_s, al_d, row_ptr, col, bb, hA, H, C);
    k_bnstats<<<256, 192, 0, stream>>>(hA, bns4 + (size_t)L*2*DIM);
  }

  hipMemsetAsync(psum, 0, (size_t)NGRAPH*DIM*4, stream);
  k_pool<<<NGRAPH*8, 192, 0, stream>>>(hA, batch, psum, pcnt);
  k_mlp<<<1, 256, 0, stream>>>(psum, pcnt, bns4 + 3*2*DIM, gam3, bet3,
                               M1,bm1,gm1,bb1, M2,bm2,gm2,bb2, M3,bm3, out);
}

// Round 5
// 1163.285 us; speedup vs baseline: 2.1481x; 1.0106x over previous
//
#include <hip/hip_runtime.h>
#include <cstdint>

#define N_NODESC 50000
#define N_EDGESC 500000
#define E_TOT    550000
#define DIM      144
#define NGRAPH   64
#define EPSV     1e-5f
#define SCAN_NB  ((N_NODESC + 511)/512)   // 98 blocks of 512 elements

__device__ __forceinline__ float lrelu(float x){ return x > 0.f ? x : 0.2f*x; }

// bf16 round-to-nearest-even pack/unpack
__device__ __forceinline__ unsigned short f2bf(float f){
  unsigned u = __float_as_uint(f);
  u += 0x7FFF + ((u >> 16) & 1);
  return (unsigned short)(u >> 16);
}
__device__ __forceinline__ float bf2f(unsigned short b){
  return __uint_as_float(((unsigned)b) << 16);
}

// ---------------- CSR build (by dst, self-loops appended) ----------------
__global__ void k_count(const int* __restrict__ ei, int* __restrict__ deg){
  int e = blockIdx.x*blockDim.x + threadIdx.x;
  if (e >= E_TOT) return;
  int d = (e < N_EDGESC) ? ei[N_EDGESC + e] : (e - N_EDGESC);
  atomicAdd(&deg[d], 1);
}

// parallel scan, stage 1: per-block (512 elems) exclusive scan + block total
__global__ __launch_bounds__(256) void k_scan1(const int* __restrict__ deg,
    int* __restrict__ scanned, int* __restrict__ bsum){
  __shared__ int ls[256];
  int b = blockIdx.x, t = threadIdx.x;
  int i0 = b*512 + 2*t;
  int e0 = (i0   < N_NODESC) ? deg[i0]   : 0;
  int e1 = (i0+1 < N_NODESC) ? deg[i0+1] : 0;
  int s = e0 + e1;
  ls[t] = s;
  __syncthreads();
  #pragma unroll
  for (int ofs=1; ofs<256; ofs<<=1){
    int v = (t >= ofs) ? ls[t-ofs] : 0;
    __syncthreads();
    ls[t] += v;
    __syncthreads();
  }
  int excl = ls[t] - s;
  if (i0   < N_NODESC) scanned[i0]   = excl;
  if (i0+1 < N_NODESC) scanned[i0+1] = excl + e0;
  if (t == 255) bsum[b] = ls[255];
}

// stage 2: exclusive scan of block totals (98 <= 128)
__global__ void k_scan2(int* __restrict__ bsum){
  __shared__ int ls[128];
  int t = threadIdx.x;
  int v = (t < SCAN_NB) ? bsum[t] : 0;
  ls[t] = v;
  __syncthreads();
  #pragma unroll
  for (int ofs=1; ofs<128; ofs<<=1){
    int u = (t >= ofs) ? ls[t-ofs] : 0;
    __syncthreads();
    ls[t] += u;
    __syncthreads();
  }
  if (t < SCAN_NB) bsum[t] = ls[t] - v;
}

// stage 3: add block offsets -> row_ptr + cursor
__global__ __launch_bounds__(256) void k_scan3(const int* __restrict__ scanned,
    const int* __restrict__ bsum, int* __restrict__ row_ptr, int* __restrict__ cursor){
  int i = blockIdx.x*blockDim.x + threadIdx.x;
  if (i < N_NODESC){
    int v = scanned[i] + bsum[i >> 9];
    row_ptr[i] = v; cursor[i] = v;
  }
  if (i == 0) row_ptr[N_NODESC] = E_TOT;
}

__global__ void k_scatter(const int* __restrict__ ei, int* __restrict__ cursor,
                          int* __restrict__ col){
  int e = blockIdx.x*blockDim.x + threadIdx.x;
  if (e >= E_TOT) return;
  int s, d;
  if (e < N_EDGESC){ s = ei[e]; d = ei[N_EDGESC + e]; } else { s = e - N_EDGESC; d = s; }
  int pos = atomicAdd(&cursor[d], 1);
  col[pos] = s;
}

// ---------------- fused GEMM + BN-on-input + attention logits ----------------
// out = BN(A)[M,K] @ W[K,144] (+bias); writes f32 (outf) OR bf16 (outb).
// Block 64 rows x 144 cols, 256 threads, 4x9 register tile per thread.
#define KC 36
#define SW_STRIDE 192   // 16 groups * 12
#define SAT_STRIDE 68
__global__ __launch_bounds__(256) void k_gemm_fused(
    const float* __restrict__ A, const float* __restrict__ W,
    const float* __restrict__ bias,
    const float* __restrict__ a_s, const float* __restrict__ a_d,
    float* __restrict__ outf, unsigned short* __restrict__ outb,
    float* __restrict__ al_s, float* __restrict__ al_d,
    int K, int H,
    const float* __restrict__ bnsum, const float* __restrict__ bngam,
    const float* __restrict__ bnbet){
  extern __shared__ float smem[];
  float* sW  = smem;                 // KC * 192
  float* sAT = smem + KC*SW_STRIDE;  // KC * 68
  float* sBN = sAT + KC*SAT_STRIDE;  // 2*144 (scale, shift)
  int t = threadIdx.x;
  int m0 = blockIdx.x * 64;
  int rg = t & 15, cg = t >> 4;
  int c0 = cg * 9;

  if (bnsum){
    for (int i=t; i<K; i+=256){
      float mu  = bnsum[i] * (1.f/N_NODESC);
      float var = bnsum[K+i] * (1.f/N_NODESC) - mu*mu;
      float inv = rsqrtf(var + EPSV);
      float sc = inv * bngam[i];
      sBN[i] = sc; sBN[K+i] = bnbet[i] - mu*sc;
    }
    __syncthreads();
  }

  float acc[4][9];
  #pragma unroll
  for (int i=0;i<4;++i)
    #pragma unroll
    for (int j=0;j<9;++j) acc[i][j] = bias ? bias[c0+j] : 0.f;

  for (int k0 = 0; k0 < K; k0 += KC){
    int kc = min(KC, K - k0);
    __syncthreads();
    for (int i = t; i < kc*144; i += 256){
      int kk = i / 144, c = i - kk*144;
      int g = c / 9, j = c - g*9;
      sW[kk*SW_STRIDE + g*12 + j] = W[(size_t)(k0+kk)*144 + c];
    }
    for (int i = t; i < 64*kc; i += 256){
      int r = i / kc, kk = i - r*kc;
      int m = m0 + r; if (m >= N_NODESC) m = N_NODESC - 1;
      float v = A[(size_t)m*K + k0 + kk];
      if (bnsum) v = fmaf(v, sBN[k0+kk], sBN[K+k0+kk]);
      sAT[kk*SAT_STRIDE + r] = v;
    }
    __syncthreads();
    for (int k = 0; k < kc; ++k){
      float4 a4 = *(const float4*)&sAT[k*SAT_STRIDE + rg*4];
      const float* wp = &sW[k*SW_STRIDE + cg*12];
      float4 w0 = *(const float4*)(wp);
      float4 w1 = *(const float4*)(wp+4);
      float  w8 = wp[8];
      float av[4] = {a4.x, a4.y, a4.z, a4.w};
      float wv[9] = {w0.x,w0.y,w0.z,w0.w,w1.x,w1.y,w1.z,w1.w,w8};
      #pragma unroll
      for (int i=0;i<4;++i)
        #pragma unroll
        for (int j=0;j<9;++j) acc[i][j] = fmaf(av[i], wv[j], acc[i][j]);
    }
  }

  if (H > 0){
    __syncthreads();
    float* sRs = smem;
    float* sRd = smem + 64*17;
    float ps[4], pd[4];
    #pragma unroll
    for (int i=0;i<4;++i){ ps[i]=0.f; pd[i]=0.f; }
    #pragma unroll
    for (int j=0;j<9;++j){
      float asj = a_s[c0+j], adj = a_d[c0+j];
      #pragma unroll
      for (int i=0;i<4;++i){ ps[i] = fmaf(acc[i][j], asj, ps[i]); pd[i] = fmaf(acc[i][j], adj, pd[i]); }
    }
    #pragma unroll
    for (int i=0;i<4;++i){
      sRs[(rg*4+i)*17 + cg] = ps[i];
      sRd[(rg*4+i)*17 + cg] = pd[i];
    }
    __syncthreads();
    int G = 16 / H;
    for (int idx = t; idx < 64*H; idx += 256){
      int r = idx / H, h = idx - r*H;
      float ss = 0.f, sd = 0.f;
      for (int g2 = h*G; g2 < (h+1)*G; ++g2){ ss += sRs[r*17+g2]; sd += sRd[r*17+g2]; }
      int m = m0 + r;
      if (m < N_NODESC){ al_s[m*H+h] = ss; al_d[m*H+h] = sd; }
    }
  }

  #pragma unroll
  for (int i=0;i<4;++i){
    int m = m0 + rg*4 + i;
    if (m < N_NODESC){
      if (outb){
        unsigned short* o = outb + (size_t)m*DIM + c0;
        #pragma unroll
        for (int j=0;j<9;++j) o[j] = f2bf(acc[i][j]);
      } else {
        float* o = outf + (size_t)m*DIM + c0;
        #pragma unroll
        for (int j=0;j<9;++j) o[j] = acc[i][j];
      }
    }
  }
}

// ---------------- per-node softmax aggregation, online chunked ----------------
// hp is bf16 (halved gather traffic); accumulation in f32.
#define ACH 64
__global__ __launch_bounds__(192) void k_aggregate(
    const unsigned short* __restrict__ hp, const float* __restrict__ al_s,
    const float* __restrict__ al_d, const int* __restrict__ row_ptr,
    const int* __restrict__ col, const float* __restrict__ bias,
    float* __restrict__ out, int H, int C){
  int n = blockIdx.x;
  int t = threadIdx.x;
  __shared__ int   s_src[ACH];
  __shared__ float s_ex[ACH*8];
  __shared__ float s_m[8], s_scale[8], s_den[8], s_ald[8];
  int p0 = row_ptr[n], p1 = row_ptr[n+1];
  if (t < H){ s_m[t] = -3.4e38f; s_den[t] = 0.f; s_ald[t] = al_d[n*H+t]; }
  int h = (t < DIM) ? (t / C) : 0;
  float acc = 0.f;

  for (int c0 = p0; c0 < p1; c0 += ACH){
    int cnt = min(ACH, p1 - c0);
    __syncthreads();                       // prev chunk fully consumed
    for (int i = t; i < cnt; i += 192) s_src[i] = col[c0 + i];
    __syncthreads();
    for (int i = t; i < cnt*H; i += 192){
      int e = i / H, hh = i - e*H;
      s_ex[e*H + hh] = lrelu(al_s[s_src[e]*H + hh] + s_ald[hh]);
    }
    __syncthreads();
    if (t < H){
      float m = s_m[t];
      for (int e = 0; e < cnt; ++e) m = fmaxf(m, s_ex[e*H + t]);
      s_scale[t] = __expf(s_m[t] - m);     // first chunk: exp(-inf)=0
      s_m[t] = m;
    }
    __syncthreads();
    for (int i = t; i < cnt*H; i += 192){
      int e = i / H, hh = i - e*H;
      s_ex[e*H + hh] = __expf(s_ex[e*H + hh] - s_m[hh]);
    }
    __syncthreads();
    if (t < H){
      float d = s_den[t] * s_scale[t];
      for (int e = 0; e < cnt; ++e) d += s_ex[e*H + t];
      s_den[t] = d;
    }
    if (t < DIM){
      acc *= s_scale[h];
      for (int e = 0; e < cnt; ++e){
        int s = s_src[e];
        acc = fmaf(s_ex[e*H + h], bf2f(hp[(size_t)s*DIM + t]), acc);
      }
    }
  }
  __syncthreads();
  if (t < DIM){
    float v = acc/(s_den[h] + 1e-16f) + bias[t];
    out[(size_t)n*DIM + t] = fmaxf(v, 0.f);   // fused ReLU
  }
}

// ---------------- batchnorm stats: register accumulate, coalesced ----------------
__global__ __launch_bounds__(192) void k_bnstats(const float* __restrict__ h,
                                                 float* __restrict__ sums){
  int t = threadIdx.x;
  if (t >= DIM) return;
  int rows = (N_NODESC + gridDim.x - 1)/gridDim.x;
  int n0 = blockIdx.x*rows, n1 = min(N_NODESC, n0+rows);
  float s = 0.f, q = 0.f;
  for (int n = n0; n < n1; ++n){
    float v = h[(size_t)n*DIM + t];
    s += v; q += v*v;
  }
  atomicAdd(&sums[t], s);
  atomicAdd(&sums[DIM+t], q);
}

// ---------------- per-graph mean pool (batch is sorted) ----------------
__device__ int lbound(const int* a, int n, int v){
  int lo = 0, hi = n;
  while (lo < hi){ int m = (lo+hi) >> 1; if (a[m] < v) lo = m+1; else hi = m; }
  return lo;
}

__global__ __launch_bounds__(192) void k_pool(const float* __restrict__ h,
    const int* __restrict__ batch, float* __restrict__ sums, int* __restrict__ cnts){
  int g = blockIdx.x & 63, part = blockIdx.x >> 6;     // 8 parts per graph
  __shared__ int sb[2];
  if (threadIdx.x == 0){ sb[0] = lbound(batch, N_NODESC, g); sb[1] = lbound(batch, N_NODESC, g+1); }
  __syncthreads();
  int lo = sb[0], hi = sb[1];
  int t = threadIdx.x;
  if (t < DIM){
    float acc = 0.f;
    for (int n = lo + part; n < hi; n += 8) acc += h[(size_t)n*DIM + t];
    atomicAdd(&sums[g*DIM + t], acc);
  }
  if (t == 0 && part == 0) cnts[g] = hi - lo;
}

// ---------------- MLP head (final BN fused into pooled-mean load) ----------------
__global__ __launch_bounds__(256) void k_mlp(const float* __restrict__ sums,
    const int* __restrict__ cnts,
    const float* __restrict__ bn3, const float* __restrict__ gam3,
    const float* __restrict__ bet3,
    const float* __restrict__ M1, const float* __restrict__ bm1,
    const float* __restrict__ gm1, const float* __restrict__ bb1,
    const float* __restrict__ M2, const float* __restrict__ bm2,
    const float* __restrict__ gm2, const float* __restrict__ bb2,
    const float* __restrict__ M3, const float* __restrict__ bm3,
    float* __restrict__ out){
  __shared__ float sg[64*144];
  __shared__ float s1[64*72];
  __shared__ float s2[64*36];
  __shared__ float stat[144];
  int t = threadIdx.x;
  for (int i=t; i<64*144; i+=256){
    int g=i/144, c=i-g*144;
    float cf=(float)max(cnts[g],1);
    float mu  = bn3[c]*(1.f/N_NODESC);
    float var = bn3[144+c]*(1.f/N_NODESC) - mu*mu;
    float inv = rsqrtf(var + EPSV);
    float sc = inv*gam3[c];
    sg[i] = (sums[i]/cf - mu)*sc + bet3[c];
  }
  __syncthreads();
  for (int i=t; i<64*72; i+=256){
    int r=i/72, c=i-r*72; float a=bm1[c];
    for (int k=0;k<144;++k) a = fmaf(sg[r*144+k], M1[k*72+c], a);
    s1[i]=a;
  }
  __syncthreads();
  if (t < 72){
    float s=0.f,q=0.f;
    for (int r=0;r<64;++r){ float v=s1[r*72+t]; s+=v; q+=v*v; }
    float mu=s*(1.f/64.f); float var=q*(1.f/64.f)-mu*mu;
    stat[t]=mu; stat[72+t]=rsqrtf(var+EPSV);
  }
  __syncthreads();
  for (int i=t; i<64*72; i+=256){
    int c=i%72; float v=fmaf((s1[i]-stat[c])*stat[72+c], gm1[c], bb1[c]); s1[i]=fmaxf(v,0.f);
  }
  __syncthreads();
  for (int i=t; i<64*36; i+=256){
    int r=i/36, c=i-r*36; float a=bm2[c];
    for (int k=0;k<72;++k) a = fmaf(s1[r*72+k], M2[k*36+c], a);
    s2[i]=a;
  }
  __syncthreads();
  if (t < 36){
    float s=0.f,q=0.f;
    for (int r=0;r<64;++r){ float v=s2[r*36+t]; s+=v; q+=v*v; }
    float mu=s*(1.f/64.f); float var=q*(1.f/64.f)-mu*mu;
    stat[t]=mu; stat[36+t]=rsqrtf(var+EPSV);
  }
  __syncthreads();
  for (int i=t; i<64*36; i+=256){
    int c=i%36; float v=fmaf((s2[i]-stat[c])*stat[36+c], gm2[c], bb2[c]); s2[i]=fmaxf(v,0.f);
  }
  __syncthreads();
  for (int i=t; i<64*112; i+=256){
    int r=i/112, c=i-r*112; float a=bm3[c];
    for (int k=0;k<36;++k) a = fmaf(s2[r*36+k], M3[k*112+c], a);
    out[i]=a;
  }
}

extern "C" void kernel_launch(void* const* d_in, const int* in_sizes, int n_in,
                              void* d_out, int out_size, void* d_ws, size_t ws_size,
                              hipStream_t stream){
  const float* x    = (const float*)d_in[0];
  const int*   ei   = (const int*)d_in[1];
  const int*   batch= (const int*)d_in[2];
  const float* We   = (const float*)d_in[3];
  const float* be   = (const float*)d_in[4];
  const float* Wg   = (const float*)d_in[5];
  const float* a_sg = (const float*)d_in[6];
  const float* a_dg = (const float*)d_in[7];
  const float* bg   = (const float*)d_in[8];
  const float* gam  = (const float*)d_in[9];
  const float* bet  = (const float*)d_in[10];
  const float* W3   = (const float*)d_in[11];
  const float* a_s3 = (const float*)d_in[12];
  const float* a_d3 = (const float*)d_in[13];
  const float* b3   = (const float*)d_in[14];
  const float* gam3 = (const float*)d_in[15];
  const float* bet3 = (const float*)d_in[16];
  const float* M1   = (const float*)d_in[17];
  const float* bm1  = (const float*)d_in[18];
  const float* gm1  = (const float*)d_in[19];
  const float* bb1  = (const float*)d_in[20];
  const float* M2   = (const float*)d_in[21];
  const float* bm2  = (const float*)d_in[22];
  const float* gm2  = (const float*)d_in[23];
  const float* bb2  = (const float*)d_in[24];
  const float* M3   = (const float*)d_in[25];
  const float* bm3  = (const float*)d_in[26];
  float* out = (float*)d_out;

  char* ws = (char*)d_ws;
  size_t off = 0;
  auto alloc = [&](size_t bytes)->char*{
    char* p = ws + off; off += (bytes + 255) & ~(size_t)255; return p;
  };
  float* hA     = (float*)alloc((size_t)N_NODESC*DIM*4);
  unsigned short* hp = (unsigned short*)alloc((size_t)N_NODESC*DIM*2);
  float* al_s   = (float*)alloc((size_t)N_NODESC*8*4);
  float* al_d   = (float*)alloc((size_t)N_NODESC*8*4);
  int* row_ptr  = (int*)alloc((size_t)(N_NODESC+1)*4);
  int* deg      = (int*)alloc((size_t)N_NODESC*4);
  int* cursor   = (int*)alloc((size_t)N_NODESC*4);
  int* scanned  = (int*)alloc((size_t)N_NODESC*4);
  int* bsum     = (int*)alloc((size_t)SCAN_NB*4);
  int* col      = (int*)alloc((size_t)E_TOT*4);
  float* bns4   = (float*)alloc(4*2*DIM*4);   // per-layer BN stats
  float* psum   = (float*)alloc((size_t)NGRAPH*DIM*4);
  int* pcnt     = (int*)alloc(NGRAPH*4);
  (void)ws_size; (void)n_in; (void)in_sizes; (void)out_size;

  const int GEMM_GRID = (N_NODESC + 63)/64;                        // 782
  const size_t GEMM_LDS = (KC*SW_STRIDE + KC*SAT_STRIDE + 2*DIM)*4; // 38592 B

  // CSR build (same graph reused by all 4 GAT layers) — parallel scan
  hipMemsetAsync(deg, 0, (size_t)N_NODESC*4, stream);
  hipMemsetAsync(bns4, 0, 4*2*DIM*4, stream);
  k_count<<<(E_TOT+255)/256, 256, 0, stream>>>(ei, deg);
  k_scan1<<<SCAN_NB, 256, 0, stream>>>(deg, scanned, bsum);
  k_scan2<<<1, 128, 0, stream>>>(bsum);
  k_scan3<<<(N_NODESC+255)/256, 256, 0, stream>>>(scanned, bsum, row_ptr, cursor);
  k_scatter<<<(E_TOT+255)/256, 256, 0, stream>>>(ei, cursor, col);

  // embed: hA = x @ We + be (f32 out)
  k_gemm_fused<<<GEMM_GRID, 256, GEMM_LDS, stream>>>(
      x, We, be, nullptr, nullptr, hA, nullptr, nullptr, nullptr, 128, 0,
      nullptr, nullptr, nullptr);

  for (int L=0; L<4; ++L){
    const float* W  = (L<3) ? (Wg  + (size_t)L*DIM*DIM) : W3;
    const float* as = (L<3) ? (a_sg + (size_t)L*8*18)   : a_s3;
    const float* ad = (L<3) ? (a_dg + (size_t)L*8*18)   : a_d3;
    const float* bb = (L<3) ? (bg  + L*DIM) : b3;
    int H = (L<3) ? 8 : 1;
    int C = (L<3) ? 18 : 144;
    // BN of the PREVIOUS layer's output is applied while staging A
    const float* bnp = (L==0) ? nullptr : bns4 + (size_t)(L-1)*2*DIM;
    const float* gmp = (L==0) ? nullptr : gam + (size_t)(L-1)*DIM;
    const float* btp = (L==0) ? nullptr : bet + (size_t)(L-1)*DIM;
    k_gemm_fused<<<GEMM_GRID, 256, GEMM_LDS, stream>>>(
        hA, W, nullptr, as, ad, nullptr, hp, al_s, al_d, DIM, H, bnp, gmp, btp);
    k_aggregate<<<N_NODESC, 192, 0, stream>>>(hp, al_s, al_d, row_ptr, col, bb, hA, H, C);
    k_bnstats<<<256, 192, 0, stream>>>(hA, bns4 + (size_t)L*2*DIM);
  }

  hipMemsetAsync(psum, 0, (size_t)NGRAPH*DIM*4, stream);
  k_pool<<<NGRAPH*8, 192, 0, stream>>>(hA, batch, psum, pcnt);
  k_mlp<<<1, 256, 0, stream>>>(psum, pcnt, bns4 + 3*2*DIM, gam3, bet3,
                               M1,bm1,gm1,bb1, M2,bm2,gm2,bb2, M3,bm3, out);
}